// Round 1
// baseline (748.593 us; speedup 1.0000x reference)
//
#include <hip/hip_runtime.h>
#include <cmath>

using f4 = __attribute__((ext_vector_type(4))) float;

constexpr int D     = 128;
constexpr int S     = 4096;
constexpr int TQ    = 64;
constexpr int TK    = 64;
constexpr int BLOCK = 256;
constexpr int PSTR  = 68;   // Ps row stride in floats (64 + 4 pad)

// LDS: Qt 32KB + Kt 32KB + Vs 32KB + Ps 17KB = 113 KB -> 1 block/CU on gfx950 (160KB)
__launch_bounds__(BLOCK, 1)
__global__ void attn_fwd_fp32(const float* __restrict__ Qg,
                              const float* __restrict__ Kg,
                              const float* __restrict__ Vg,
                              float* __restrict__ Og) {
  __shared__ float Qt[D * TQ];     // [d][row]  transposed, scaled by 1/sqrt(D)
  __shared__ float Kt[D * TK];     // [d][key]  transposed
  __shared__ float Vs[TK * D];     // [key][d]  row-major
  __shared__ float Ps[TQ * PSTR];  // [row][key]

  const int tid = threadIdx.x;
  const int tx  = tid & 15;   // score cols 4*tx..4*tx+3 ; O cols 8*tx..8*tx+7
  const int ty  = tid >> 4;   // score/O rows 4*ty..4*ty+3
  const int b   = blockIdx.y;
  const int q0  = blockIdx.x * TQ;

  const float* Qb = Qg + ((size_t)b * S + q0) * D;
  const float* Kb = Kg + (size_t)b * S * D;
  const float* Vb = Vg + (size_t)b * S * D;
  float*       Ob = Og + ((size_t)b * S + q0) * D;

  constexpr float scale = 0.08838834764831845f;  // 1/sqrt(128)

  // ---- stage Q transposed (pre-scaled). Writes: banks = r%32, conflict-free.
  {
    const int r  = tid & 63;
    const int c0 = (tid >> 6) * 4;  // 0,4,8,12
    #pragma unroll
    for (int cc = 0; cc < D; cc += 16) {
      const int c = c0 + cc;
      f4 v = *(const f4*)(Qb + (size_t)r * D + c);
      Qt[(c + 0) * TQ + r] = v[0] * scale;
      Qt[(c + 1) * TQ + r] = v[1] * scale;
      Qt[(c + 2) * TQ + r] = v[2] * scale;
      Qt[(c + 3) * TQ + r] = v[3] * scale;
    }
  }

  float m_i[4], l_i[4];
  float acc[4][8];
  #pragma unroll
  for (int i = 0; i < 4; ++i) {
    m_i[i] = -INFINITY;
    l_i[i] = 0.f;
    #pragma unroll
    for (int c = 0; c < 8; ++c) acc[i][c] = 0.f;
  }

  for (int kt = 0; kt < S / TK; ++kt) {
    const float* Kgt = Kb + (size_t)kt * TK * D;
    const float* Vgt = Vb + (size_t)kt * TK * D;

    __syncthreads();  // previous iteration's LDS reads (Kt/Vs/Ps) are done

    // ---- stage K transposed
    {
      const int r  = tid & 63;
      const int c0 = (tid >> 6) * 4;
      #pragma unroll
      for (int cc = 0; cc < D; cc += 16) {
        const int c = c0 + cc;
        f4 v = *(const f4*)(Kgt + (size_t)r * D + c);
        Kt[(c + 0) * TK + r] = v[0];
        Kt[(c + 1) * TK + r] = v[1];
        Kt[(c + 2) * TK + r] = v[2];
        Kt[(c + 3) * TK + r] = v[3];
      }
    }
    // ---- stage V row-major (coalesced f4 -> f4)
    #pragma unroll
    for (int it = 0; it < 8; ++it) {
      const int i  = tid + it * BLOCK;
      const int rr = i >> 5;
      const int c4 = (i & 31) << 2;
      *(f4*)(&Vs[rr * D + c4]) = *(const f4*)(Vgt + (size_t)rr * D + c4);
    }
    __syncthreads();

    // ---- S = (Q*scale) K^T : 4x4 register tile per thread
    float s[4][4];
    #pragma unroll
    for (int i = 0; i < 4; ++i)
      #pragma unroll
      for (int j = 0; j < 4; ++j) s[i][j] = 0.f;

    #pragma unroll 4
    for (int d = 0; d < D; ++d) {
      f4 q = *(const f4*)(&Qt[d * TQ + 4 * ty]);  // rows 4ty..4ty+3, broadcast over tx
      f4 k = *(const f4*)(&Kt[d * TK + 4 * tx]);  // keys 4tx..4tx+3, 2-way (free)
      #pragma unroll
      for (int i = 0; i < 4; ++i)
        #pragma unroll
        for (int j = 0; j < 4; ++j)
          s[i][j] = fmaf(q[i], k[j], s[i][j]);
    }

    // ---- online softmax; row stats reduced over the 16 tx lanes (within wave)
    #pragma unroll
    for (int i = 0; i < 4; ++i) {
      float rm = fmaxf(fmaxf(s[i][0], s[i][1]), fmaxf(s[i][2], s[i][3]));
      #pragma unroll
      for (int off = 1; off < 16; off <<= 1)
        rm = fmaxf(rm, __shfl_xor(rm, off, 64));
      const float mn    = fmaxf(m_i[i], rm);
      const float alpha = __expf(m_i[i] - mn);  // first tile: exp(-inf)=0
      float rs = 0.f;
      #pragma unroll
      for (int j = 0; j < 4; ++j) {
        const float p = __expf(s[i][j] - mn);
        Ps[(4 * ty + i) * PSTR + 4 * tx + j] = p;
        rs += p;
      }
      #pragma unroll
      for (int off = 1; off < 16; off <<= 1)
        rs += __shfl_xor(rs, off, 64);
      l_i[i] = l_i[i] * alpha + rs;
      m_i[i] = mn;
      #pragma unroll
      for (int c = 0; c < 8; ++c) acc[i][c] *= alpha;
    }
    __syncthreads();  // Ps visible to all

    // ---- O += P V
    #pragma unroll 2
    for (int k = 0; k < TK; ++k) {
      f4 va = *(const f4*)(&Vs[k * D + 8 * tx]);      // 4-way conflict (~1.58x), ok
      f4 vb = *(const f4*)(&Vs[k * D + 8 * tx + 4]);
      const float p0 = Ps[(4 * ty + 0) * PSTR + k];   // broadcast over tx
      const float p1 = Ps[(4 * ty + 1) * PSTR + k];
      const float p2 = Ps[(4 * ty + 2) * PSTR + k];
      const float p3 = Ps[(4 * ty + 3) * PSTR + k];
      #pragma unroll
      for (int c = 0; c < 4; ++c) {
        acc[0][c]     = fmaf(p0, va[c], acc[0][c]);
        acc[1][c]     = fmaf(p1, va[c], acc[1][c]);
        acc[2][c]     = fmaf(p2, va[c], acc[2][c]);
        acc[3][c]     = fmaf(p3, va[c], acc[3][c]);
        acc[0][4 + c] = fmaf(p0, vb[c], acc[0][4 + c]);
        acc[1][4 + c] = fmaf(p1, vb[c], acc[1][4 + c]);
        acc[2][4 + c] = fmaf(p2, vb[c], acc[2][4 + c]);
        acc[3][4 + c] = fmaf(p3, vb[c], acc[3][4 + c]);
      }
    }
  }

  // ---- epilogue: normalize and store
  #pragma unroll
  for (int i = 0; i < 4; ++i) {
    const float inv = 1.0f / l_i[i];
    f4 o0 = {acc[i][0] * inv, acc[i][1] * inv, acc[i][2] * inv, acc[i][3] * inv};
    f4 o1 = {acc[i][4] * inv, acc[i][5] * inv, acc[i][6] * inv, acc[i][7] * inv};
    float* op = Ob + (size_t)(4 * ty + i) * D + 8 * tx;
    *(f4*)(op)     = o0;
    *(f4*)(op + 4) = o1;
  }
}

extern "C" void kernel_launch(void* const* d_in, const int* in_sizes, int n_in,
                              void* d_out, int out_size, void* d_ws, size_t ws_size,
                              hipStream_t stream) {
  const float* q = (const float*)d_in[0];
  const float* k = (const float*)d_in[1];
  const float* v = (const float*)d_in[2];
  float* out     = (float*)d_out;

  const int Bn = in_sizes[0] / (S * D);  // = 4
  dim3 grid(S / TQ, Bn);
  dim3 block(BLOCK);
  hipLaunchKernelGGL(attn_fwd_fp32, grid, block, 0, stream, q, k, v, out);
}

// Round 4
// 201.846 us; speedup vs baseline: 3.7087x; 3.7087x over previous
//
#include <hip/hip_runtime.h>
#include <cmath>
#include <cstdint>

typedef __attribute__((ext_vector_type(8))) __bf16 bf16x8;
typedef __attribute__((ext_vector_type(16))) float f32x16;
typedef unsigned int u32;
typedef unsigned short u16;

constexpr int Bn = 4, Sn = 4096, Dn = 128;
constexpr int TQ = 64, TK = 64;
constexpr int KSTR = 136;  // Ks row stride in bf16 (128 + 8 pad)
constexpr int VSTR = 72;   // Vt row stride in bf16 (64 + 8 pad)
constexpr int OSTR = 132;  // Oc row stride in f32 (128 + 4 pad, keeps 16B align)
constexpr float SCL2E = 0.08838834764831845f * 1.4426950408889634f;  // 1/sqrt(128)*log2(e)

__device__ __forceinline__ u16 bfr(float x) {  // fp32 -> bf16 RNE
  u32 u = __builtin_bit_cast(u32, x);
  return (u16)((u + 0x7fffu + ((u >> 16) & 1u)) >> 16);
}
__device__ __forceinline__ u32 pk2(float a, float b) {  // pack 2 fp32 -> bf16x2 (RNE)
  return (u32)bfr(a) | ((u32)bfr(b) << 16);
}

// ---- pre-pass: Q (scaled) and K -> bf16, same layout ----
__global__ void cvt_qk(const float* __restrict__ q, const float* __restrict__ k,
                       u16* __restrict__ qo, u16* __restrict__ ko) {
  const int i = (blockIdx.x * blockDim.x + threadIdx.x) * 4;
  float4 qv = *(const float4*)(q + i);
  ushort4 a;
  a.x = bfr(qv.x * SCL2E); a.y = bfr(qv.y * SCL2E);
  a.z = bfr(qv.z * SCL2E); a.w = bfr(qv.w * SCL2E);
  *(ushort4*)(qo + i) = a;
  float4 kv = *(const float4*)(k + i);
  ushort4 c;
  c.x = bfr(kv.x); c.y = bfr(kv.y); c.z = bfr(kv.z); c.w = bfr(kv.w);
  *(ushort4*)(ko + i) = c;
}

// ---- pre-pass: V [B][S][D] fp32 -> Vt [B][D][S] bf16 (LDS tile transpose) ----
__global__ void cvt_vt(const float* __restrict__ v, u16* __restrict__ vt) {
  __shared__ u16 tile[32][33];
  const int s0 = blockIdx.x * 32, d0 = blockIdx.y * 32, b = blockIdx.z;
  const float* vb = v + (size_t)b * Sn * Dn;
  u16* vtb = vt + (size_t)b * Sn * Dn;
  const int tx = threadIdx.x, ty = threadIdx.y;
  #pragma unroll
  for (int r = 0; r < 4; ++r) {
    const int s = s0 + ty + r * 8;
    tile[ty + r * 8][tx] = bfr(vb[(size_t)s * Dn + d0 + tx]);
  }
  __syncthreads();
  #pragma unroll
  for (int r = 0; r < 4; ++r) {
    const int d = d0 + ty + r * 8;
    vtb[(size_t)d * Sn + s0 + tx] = tile[tx][ty + r * 8];
  }
}

// ---- main: flash attention, 32x32x16 bf16 MFMA ----
// 512 thr = 8 waves = (qh in {0,1}) x (kp in {0..3}); TQ=64 q-rows per block.
// Wave computes S^T = K.Q^T (A=K LDS, B=Q regs) -> q = C-col = lane&31.
// Then O^T = V^T.P^T (A=V from transposed-V LDS, B=P via xor-32 butterfly),
// so accO keeps q = col = lane&31 -> per-lane alpha/l rescale is exact.
__launch_bounds__(512, 2)
__global__ void attn_mfma(const u16* __restrict__ qb, const u16* __restrict__ kb,
                          const u16* __restrict__ vtg, float* __restrict__ Og) {
  __shared__ __align__(16) unsigned char lds[145408];
  u16* Ks = (u16*)lds;                    // [4][64][KSTR]
  u16* Vt = (u16*)(lds + 69632);          // [4][128][VSTR]
  float* ml = (float*)(lds + 143360);     // [2][4][32][2]
  float* Oc = (float*)lds;                // [2][4][32][OSTR] (reuses staging, post-barrier)

  const int tid = threadIdx.x;
  const int w = tid >> 6, lane = tid & 63;
  const int c = lane & 31, h = lane >> 5;
  const int qh = w & 1, kp = w >> 1;
  const int b = blockIdx.y;
  const int q0 = blockIdx.x * TQ;

  const u16* Qp = qb + ((size_t)b * Sn + q0 + qh * 32) * Dn;
  const u16* Kp = kb + (size_t)b * Sn * Dn;
  const u16* Vp = vtg + (size_t)b * Sn * Dn;  // [D][S]

  // persistent Q B-frags: B[k=d][n=q], lane holds n=c, k = kc*16 + h*8 + j
  bf16x8 qf[8];
  #pragma unroll
  for (int kc = 0; kc < 8; ++kc) {
    uint4 t = *(const uint4*)(Qp + (size_t)c * Dn + kc * 16 + h * 8);
    qf[kc] = __builtin_bit_cast(bf16x8, t);
  }

  f32x16 accO[4];
  #pragma unroll
  for (int nt = 0; nt < 4; ++nt)
    #pragma unroll
    for (int r = 0; r < 16; ++r) accO[nt][r] = 0.f;
  float m_i = -INFINITY, l_i = 0.f;

  u16* Ksb = Ks + kp * (64 * KSTR);
  u16* Vtb = Vt + kp * (128 * VSTR);

  #pragma unroll 1
  for (int it = 0; it < (Sn / TK) / 4; ++it) {
    const int kt = it * 4 + kp;
    __syncthreads();
    {  // stage K tile: rows=keys, coalesced 256B segments
      const int key = (lane >> 4) + qh * 32;
      const int d0 = (lane & 15) * 8;
      const u16* src = Kp + ((size_t)kt * TK + key) * Dn + d0;
      u16* dst = Ksb + key * KSTR + d0;
      #pragma unroll
      for (int r = 0; r < 8; ++r)
        *(uint4*)(dst + r * 4 * KSTR) = *(const uint4*)(src + r * 4 * Dn);
    }
    {  // stage V tile from pre-transposed global: rows=d, 128B segments
      const int d = (lane >> 3) + qh * 64;
      const int k8 = (lane & 7) * 8;
      const u16* src = Vp + (size_t)d * Sn + kt * TK + k8;
      u16* dst = Vtb + d * VSTR + k8;
      #pragma unroll
      for (int r = 0; r < 8; ++r)
        *(uint4*)(dst + r * 8 * VSTR) = *(const uint4*)(src + (size_t)r * 8 * Sn);
    }
    __syncthreads();

    // S^T = K.Q^T : two 32-key M-tiles, K=128 over 8 chunks
    f32x16 sa0, sa1;
    #pragma unroll
    for (int r = 0; r < 16; ++r) { sa0[r] = 0.f; sa1[r] = 0.f; }
    #pragma unroll
    for (int kc = 0; kc < 8; ++kc) {
      bf16x8 a0 = __builtin_bit_cast(bf16x8, *(const uint4*)(Ksb + c * KSTR + kc * 16 + h * 8));
      bf16x8 a1 = __builtin_bit_cast(bf16x8, *(const uint4*)(Ksb + (32 + c) * KSTR + kc * 16 + h * 8));
      sa0 = __builtin_amdgcn_mfma_f32_32x32x16_bf16(a0, qf[kc], sa0, 0, 0, 0);
      sa1 = __builtin_amdgcn_mfma_f32_32x32x16_bf16(a1, qf[kc], sa1, 0, 0, 0);
    }

    // online softmax (exp2 domain; scale*log2e folded into Q). q = c per lane.
    float mx = sa0[0];
    #pragma unroll
    for (int r = 1; r < 16; ++r) mx = fmaxf(mx, sa0[r]);
    #pragma unroll
    for (int r = 0; r < 16; ++r) mx = fmaxf(mx, sa1[r]);
    mx = fmaxf(mx, __shfl_xor(mx, 32));
    const float mnew = fmaxf(m_i, mx);
    const float alpha = exp2f(m_i - mnew);  // first tile: exp2(-inf)=0
    float rs = 0.f;
    #pragma unroll
    for (int r = 0; r < 16; ++r) { sa0[r] = exp2f(sa0[r] - mnew); rs += sa0[r]; }
    #pragma unroll
    for (int r = 0; r < 16; ++r) { sa1[r] = exp2f(sa1[r] - mnew); rs += sa1[r]; }
    rs += __shfl_xor(rs, 32);
    l_i = l_i * alpha + rs;
    m_i = mnew;
    // accO col = q = c  ->  per-lane alpha applies to ALL 64 entries correctly
    #pragma unroll
    for (int nt = 0; nt < 4; ++nt)
      #pragma unroll
      for (int r = 0; r < 16; ++r) accO[nt][r] *= alpha;

    // pack P to bf16 pairs (adjacent C-regs = adjacent keys)
    u32 pk[2][8];
    #pragma unroll
    for (int i = 0; i < 8; ++i) {
      pk[0][i] = pk2(sa0[2 * i], sa0[2 * i + 1]);
      pk[1][i] = pk2(sa1[2 * i], sa1[2 * i + 1]);
    }

    // O^T += V^T.P^T : A = Vt b128 reads (m=d), B = P via xor-32 butterfly (n=q)
    #pragma unroll
    for (int kc2 = 0; kc2 < 4; ++kc2) {
      const int t = kc2 >> 1;
      const int bb = (kc2 & 1) * 4;
      u32 o0 = pk[t][bb], o1 = pk[t][bb + 1], o2 = pk[t][bb + 2], o3 = pk[t][bb + 3];
      u32 r0 = (u32)__shfl_xor((int)o0, 32);
      u32 r1 = (u32)__shfl_xor((int)o1, 32);
      u32 r2 = (u32)__shfl_xor((int)o2, 32);
      u32 r3 = (u32)__shfl_xor((int)o3, 32);
      uint4 afi;
      afi.x = h ? r2 : o0;   // keys +0,1 of this lane's 8-key strip
      afi.y = h ? r3 : o1;   // keys +2,3
      afi.z = h ? o2 : r0;   // keys +4,5
      afi.w = h ? o3 : r1;   // keys +6,7
      bf16x8 af = __builtin_bit_cast(bf16x8, afi);
      #pragma unroll
      for (int nt = 0; nt < 4; ++nt) {
        bf16x8 av = __builtin_bit_cast(
            bf16x8, *(const uint4*)(Vtb + (nt * 32 + c) * VSTR + kc2 * 16 + h * 8));
        accO[nt] = __builtin_amdgcn_mfma_f32_32x32x16_bf16(av, af, accO[nt], 0, 0, 0);
      }
    }
  }

  // ---- 4-way kp combine through LDS ----
  __syncthreads();
  {
    float* od = Oc + (size_t)((qh * 4 + kp) * 32) * OSTR;
    #pragma unroll
    for (int nt = 0; nt < 4; ++nt)
      #pragma unroll
      for (int r = 0; r < 16; ++r) {
        const int dr = (r & 3) + 8 * (r >> 2) + 4 * h;  // d within 32-block
        od[c * OSTR + nt * 32 + dr] = accO[nt][r];       // row = query = c
      }
    if (h == 0) {
      float* mp = ml + ((qh * 4 + kp) * 32 + c) * 2;
      mp[0] = m_i;
      mp[1] = l_i;
    }
  }
  __syncthreads();
  {
    const int ql = tid >> 3;           // 0..63 output row
    const int qh2 = ql >> 5, qq = ql & 31;
    const int d0 = (tid & 7) * 16;
    float mstar = -INFINITY;
    float mm[4], lv[4];
    #pragma unroll
    for (int k2 = 0; k2 < 4; ++k2) {
      const float* mp = ml + ((qh2 * 4 + k2) * 32 + qq) * 2;
      mm[k2] = mp[0]; lv[k2] = mp[1];
      mstar = fmaxf(mstar, mm[k2]);
    }
    float lstar = 0.f, wgt[4];
    #pragma unroll
    for (int k2 = 0; k2 < 4; ++k2) { wgt[k2] = exp2f(mm[k2] - mstar); lstar += wgt[k2] * lv[k2]; }
    const float inv = 1.f / lstar;
    float4 acc[4];
    #pragma unroll
    for (int j = 0; j < 4; ++j) acc[j] = float4{0.f, 0.f, 0.f, 0.f};
    #pragma unroll
    for (int k2 = 0; k2 < 4; ++k2) {
      const float* oc = Oc + (size_t)((qh2 * 4 + k2) * 32 + qq) * OSTR + d0;
      #pragma unroll
      for (int j = 0; j < 4; ++j) {
        float4 vv = *(const float4*)(oc + 4 * j);
        acc[j].x += wgt[k2] * vv.x; acc[j].y += wgt[k2] * vv.y;
        acc[j].z += wgt[k2] * vv.z; acc[j].w += wgt[k2] * vv.w;
      }
    }
    float* op = Og + ((size_t)b * Sn + q0 + ql) * Dn + d0;
    #pragma unroll
    for (int j = 0; j < 4; ++j) {
      float4 o = {acc[j].x * inv, acc[j].y * inv, acc[j].z * inv, acc[j].w * inv};
      *(float4*)(op + 4 * j) = o;
    }
  }
}

extern "C" void kernel_launch(void* const* d_in, const int* in_sizes, int n_in,
                              void* d_out, int out_size, void* d_ws, size_t ws_size,
                              hipStream_t stream) {
  const float* q = (const float*)d_in[0];
  const float* k = (const float*)d_in[1];
  const float* v = (const float*)d_in[2];
  float* out = (float*)d_out;
  const size_t N = (size_t)Bn * Sn * Dn;  // 2,097,152 elems; needs 12.6 MB ws
  u16* qb = (u16*)d_ws;
  u16* kb = qb + N;
  u16* vt = kb + N;

  cvt_qk<<<dim3((unsigned)(N / 1024)), dim3(256), 0, stream>>>(q, k, qb, kb);
  cvt_vt<<<dim3(Sn / 32, Dn / 32, Bn), dim3(32, 8), 0, stream>>>(v, vt);
  attn_mfma<<<dim3(Sn / TQ, Bn), dim3(512), 0, stream>>>(qb, kb, vt, out);
}